// Round 9
// baseline (122.982 us; speedup 1.0000x reference)
//
#include <hip/hip_runtime.h>

#define DEV __device__ __forceinline__

typedef _Float16 half8 __attribute__((ext_vector_type(8)));
typedef _Float16 half2v __attribute__((ext_vector_type(2)));
typedef float f32x16 __attribute__((ext_vector_type(16)));
typedef int int4v __attribute__((ext_vector_type(4)));

DEV f32x16 mfma16(half8 a, half8 b, f32x16 c) {
    return __builtin_amdgcn_mfma_f32_32x32x16_f16(a, b, c, 0, 0, 0);
}
DEV half8 h8(int4v v) { return __builtin_bit_cast(half8, v); }
DEV half8 ldh8(const _Float16* p) { return *(const half8*)p; }
DEV int pkrtz(float a, float b) {
    auto t = __builtin_amdgcn_cvt_pkrtz(a, b);
    return __builtin_bit_cast(int, t);
}
// pack two f32 -> f16x2 (RTZ), then packed relu
DEV int relupk(float a, float b) {
    int p = pkrtz(a, b);
    half2v h = __builtin_bit_cast(half2v, p);
    half2v z = {(_Float16)0.f, (_Float16)0.f};
    h = __builtin_elementwise_max(h, z);   // v_pk_max_f16
    return __builtin_bit_cast(int, h);
}
// v_permlane32_swap_b32: a[32..63] <-> b[0..31]
DEV void plswap(int& a, int& b) {
    asm("v_permlane32_swap_b32 %0, %1" : "+v"(a), "+v"(b));
}

DEV f32x16 zero16() {
    f32x16 z = {0.f,0.f,0.f,0.f,0.f,0.f,0.f,0.f,0.f,0.f,0.f,0.f,0.f,0.f,0.f,0.f};
    return z;
}

struct Frags { int4v c[4]; };  // activation B-fragments, K=64 (4 chunks of 16)

// relu + pack + cross-half swap: D-layout -> next layer's B-frag layout (verified R0)
DEV void repack(const f32x16& C0, const f32x16& C1, Frags& B) {
    int P0[8], P1[8];
#pragma unroll
    for (int q = 0; q < 8; ++q) {
        P0[q] = relupk(C0[2*q], C0[2*q+1]);
        P1[q] = relupk(C1[2*q], C1[2*q+1]);
    }
#pragma unroll
    for (int kk = 0; kk < 4; ++kk) {
        const int* Pm = (kk < 2) ? P0 : P1;
        int idx = 4 * (kk & 1);
        int a0 = Pm[idx + 0], b0 = Pm[idx + 2];
        int a1 = Pm[idx + 1], b1 = Pm[idx + 3];
        plswap(a0, b0);
        plswap(a1, b1);
        int4v nb; nb[0] = a0; nb[1] = a1; nb[2] = b0; nb[3] = b1;
        B.c[kk] = nb;
    }
}

// issue the 10 ds_read_b128 for one hidden layer's A-fragments (5 chunks x 2 m-halves)
DEV void loadA5(const _Float16* base, int lam, half8* A0, half8* A1) {
    const _Float16* p0 = base + lam * 8;
    const _Float16* p1 = base + 2560 + lam * 8;
#pragma unroll
    for (int kk = 0; kk < 5; ++kk) {
        A0[kk] = ldh8(p0 + kk * 512);
        A1[kk] = ldh8(p1 + kk * 512);
    }
}

// hidden layer compute from preloaded A-frags: T=2, 4 accumulators
DEV void step2(const half8* A0, const half8* A1, int4v ones, Frags& B0, Frags& B1) {
    __builtin_amdgcn_s_setprio(1);
    f32x16 C00 = mfma16(A0[4], h8(ones), zero16());
    f32x16 C01 = mfma16(A1[4], h8(ones), zero16());
    f32x16 C10 = mfma16(A0[4], h8(ones), zero16());
    f32x16 C11 = mfma16(A1[4], h8(ones), zero16());
#pragma unroll
    for (int kk = 0; kk < 4; ++kk) {
        half8 b0 = h8(B0.c[kk]);
        half8 b1 = h8(B1.c[kk]);
        C00 = mfma16(A0[kk], b0, C00);
        C01 = mfma16(A1[kk], b0, C01);
        C10 = mfma16(A0[kk], b1, C10);
        C11 = mfma16(A1[kk], b1, C11);
    }
    __builtin_amdgcn_s_setprio(0);
    repack(C00, C01, B0);
    repack(C10, C11, B1);
}

// input layer from hoisted wI frags: K=32 (bias rides in k=28 slot of x)
DEV void in_step(const half8* I0, const half8* I1, Frags& B0, Frags& B1) {
    __builtin_amdgcn_s_setprio(1);
    f32x16 C00 = mfma16(I0[0], h8(B0.c[0]), zero16());
    f32x16 C01 = mfma16(I1[0], h8(B0.c[0]), zero16());
    f32x16 C10 = mfma16(I0[0], h8(B1.c[0]), zero16());
    f32x16 C11 = mfma16(I1[0], h8(B1.c[0]), zero16());
    C00 = mfma16(I0[1], h8(B0.c[1]), C00);
    C01 = mfma16(I1[1], h8(B0.c[1]), C01);
    C10 = mfma16(I0[1], h8(B1.c[1]), C10);
    C11 = mfma16(I1[1], h8(B1.c[1]), C11);
    __builtin_amdgcn_s_setprio(0);
    repack(C00, C01, B0);
    repack(C10, C11, B1);
}

// out layer from hoisted wO frags: features 0..20, A shared across the pair
DEV void out_step(const half8* Ao, int lam, int4v ones,
                  const Frags& B0, const Frags& B1, float* __restrict__ out, int row0, int row1) {
    const int h = lam >> 5;
    __builtin_amdgcn_s_setprio(1);
    f32x16 Ca = mfma16(Ao[4], h8(ones), zero16());
    f32x16 Cb = mfma16(Ao[4], h8(ones), zero16());
#pragma unroll
    for (int kk = 0; kk < 4; ++kk) {
        Ca = mfma16(Ao[kk], h8(B0.c[kk]), Ca);
        Cb = mfma16(Ao[kk], h8(B1.c[kk]), Cb);
    }
    __builtin_amdgcn_s_setprio(0);
    float* oa = out + row0 * 21;
    float* ob = out + row1 * 21;
#pragma unroll
    for (int r = 0; r < 16; ++r) {
        int f = (r & 3) + 8 * (r >> 2) + 4 * h;
        if (f < 21) {
            oa[f] = __builtin_amdgcn_rcpf(1.f + __expf(-Ca[r]));
            ob[f] = __builtin_amdgcn_rcpf(1.f + __expf(-Cb[r]));
        }
    }
}

DEV void load_x(const float* __restrict__ x, int row, int h, Frags& B) {
    // k = 16*kk + 8*h + e; x row stride 28 f32; k=28 slot carries 1.0 (bias rides in wI row 28)
    const float* xr = x + row * 28;
    float4 fa = *(const float4*)(xr + 8 * h);
    float4 fb = *(const float4*)(xr + 8 * h + 4);
    float4 fc = *(const float4*)(xr + 16 + 8 * h);
    float4 fd = (h == 0) ? *(const float4*)(xr + 20) : make_float4(1.f, 0.f, 0.f, 0.f);
    int4v c0, c1;
    c0[0] = pkrtz(fa.x, fa.y); c0[1] = pkrtz(fa.z, fa.w);
    c0[2] = pkrtz(fb.x, fb.y); c0[3] = pkrtz(fb.z, fb.w);
    c1[0] = pkrtz(fc.x, fc.y); c1[1] = pkrtz(fc.z, fc.w);
    c1[2] = pkrtz(fd.x, fd.y); c1[3] = pkrtz(fd.z, fd.w);
    B.c[0] = c0; B.c[1] = c1;
}

#define NT 512

__global__ __attribute__((amdgpu_flat_work_group_size(NT, NT), amdgpu_waves_per_eu(2, 2)))
void mlp_fused(
    const float* __restrict__ x, const float* __restrict__ W_in, const float* __restrict__ b_in,
    const float* __restrict__ W_hid, const float* __restrict__ b_hid,
    const float* __restrict__ W_out, const float* __restrict__ b_out,
    float* __restrict__ out) {
    // LDS weights in f16, A-fragment order: wH [l][m][kk 0..4][lam][e]; chunk kk=4 = bias column
    // wH has an 11th dummy layer so the pipeline's last prefetch is branch-free.
    __shared__ __align__(16) _Float16 wH[56320];  // 11 x 2 x 5 x 64 x 8 (layer 10 = pad, never used)
    __shared__ __align__(16) _Float16 wI[2048];   // 2 x 2 x 64 x 8  (K=32, bias in k=28)
    __shared__ __align__(16) _Float16 wO[2560];   // 5 x 64 x 8      (features 0..20)

    const int tid = threadIdx.x;

    // zero phase: chunk-4 regions of wH, all of wI and wO
    for (int i = tid; i < 10240; i += NT) {   // wH bias chunks: [l][m][512]
        int l = i >> 10, rem = i & 1023, m = rem >> 9, off = rem & 511;
        wH[l * 5120 + m * 2560 + 2048 + off] = (_Float16)0.f;
    }
    for (int i = tid; i < 2048; i += NT) wI[i] = (_Float16)0.f;
    for (int i = tid; i < 2560; i += NT) wO[i] = (_Float16)0.f;
    __syncthreads();

    // fill phase (coalesced global reads, scattered LDS writes)
    for (int i = tid; i < 40960; i += NT) {   // W_hid [l][kin][o]
        int o = i & 63, kin = (i >> 6) & 63, l = i >> 12;
        int m = o >> 5, kk = kin >> 4, hh = (kin >> 3) & 1, e = kin & 7;
        int lam = hh * 32 + (o & 31);
        wH[l * 5120 + m * 2560 + kk * 512 + lam * 8 + e] = (_Float16)W_hid[i];
    }
    for (int i = tid; i < 640; i += NT) {     // b_hid -> wH chunk4, e=0, lam<32
        int l = i >> 6, f = i & 63, m = f >> 5, r = f & 31;
        wH[l * 5120 + m * 2560 + 2048 + r * 8] = (_Float16)b_hid[i];
    }
    for (int i = tid; i < 1792; i += NT) {    // W_in [28][64]
        int o = i & 63, kin = i >> 6;
        int m = o >> 5, kk = kin >> 4, hh = (kin >> 3) & 1, e = kin & 7;
        int lam = hh * 32 + (o & 31);
        wI[m * 1024 + kk * 512 + lam * 8 + e] = (_Float16)W_in[i];
    }
    for (int i = tid; i < 64; i += NT) {      // b_in -> wI k=28 slot: kk=1, hh=1, e=4
        int m = i >> 5;
        wI[m * 1024 + 512 + (32 + (i & 31)) * 8 + 4] = (_Float16)b_in[i];
    }
    for (int i = tid; i < 1344; i += NT) {    // W_out [64][21]
        int o = i % 21, kin = i / 21;
        int kk = kin >> 4, hh = (kin >> 3) & 1, e = kin & 7;
        int lam = hh * 32 + o;
        wO[kk * 512 + lam * 8 + e] = (_Float16)W_out[i];
    }
    for (int i = tid; i < 21; i += NT)        // b_out -> wO chunk4, e=0
        wO[4 * 512 + i * 8] = (_Float16)b_out[i];
    __syncthreads();

    const int w = tid >> 6, lam = tid & 63;
    const int col = lam & 31, h = lam >> 5;
    int4v ones; ones[0] = (h == 0) ? 0x3C00 : 0; ones[1] = 0; ones[2] = 0; ones[3] = 0;

    // hoist loop-invariant input/output layer fragments into registers (reused by all pairs)
    half8 I0[2], I1[2], Ao[5];
    {
        const _Float16* p0 = wI + lam * 8;
        const _Float16* p1 = wI + 1024 + lam * 8;
#pragma unroll
        for (int kk = 0; kk < 2; ++kk) {
            I0[kk] = ldh8(p0 + kk * 512);
            I1[kk] = ldh8(p1 + kk * 512);
        }
        const _Float16* po = wO + lam * 8;
#pragma unroll
        for (int kk = 0; kk < 5; ++kk) Ao[kk] = ldh8(po + kk * 512);
    }

    // anti-convoy: odd waves start ~832 cycles late
    if (w & 1) __builtin_amdgcn_s_sleep(13);

    // persistent: 256 blocks x 64 pairs; wave w takes pairs w*8 .. w*8+7
    const int tbase = blockIdx.x * 128;
#pragma unroll 1
    for (int j = 0; j < 8; ++j) {
        int p = w * 8 + j;
        int t0 = tbase + p * 2;
        int row0 = t0 * 32 + col, row1 = row0 + 32;
        Frags B0, B1;
        load_x(x, row0, h, B0);
        load_x(x, row1, h, B1);
        half8 Aa0[5], Aa1[5], Ab0[5], Ab1[5];
        loadA5(wH, lam, Aa0, Aa1);        // issue layer-0 reads; latency hides under in_step
        in_step(I0, I1, B0, B1);
        const _Float16* base = wH;
#pragma unroll 1
        for (int l2 = 0; l2 < 5; ++l2) {
            loadA5(base + 5120, lam, Ab0, Ab1);   // prefetch layer 2*l2+1
            step2(Aa0, Aa1, ones, B0, B1);        // compute layer 2*l2
            loadA5(base + 10240, lam, Aa0, Aa1);  // prefetch layer 2*l2+2 (pad layer when l2==4)
            step2(Ab0, Ab1, ones, B0, B1);        // compute layer 2*l2+1
            base += 10240;
        }
        out_step(Ao, lam, ones, B0, B1, out, row0, row1);
    }
}

extern "C" void kernel_launch(void* const* d_in, const int* in_sizes, int n_in,
                              void* d_out, int out_size, void* d_ws, size_t ws_size,
                              hipStream_t stream) {
    const float* x     = (const float*)d_in[0];
    const float* W_in  = (const float*)d_in[1];
    const float* b_in  = (const float*)d_in[2];
    const float* W_hid = (const float*)d_in[3];
    const float* b_hid = (const float*)d_in[4];
    const float* W_out = (const float*)d_in[5];
    const float* b_out = (const float*)d_in[6];
    float* out = (float*)d_out;
    mlp_fused<<<dim3(256), dim3(NT), 0, stream>>>(x, W_in, b_in, W_hid, b_hid, W_out, b_out, out);
}

// Round 10
// 100.674 us; speedup vs baseline: 1.2216x; 1.2216x over previous
//
#include <hip/hip_runtime.h>

#define DEV __device__ __forceinline__

typedef _Float16 half8 __attribute__((ext_vector_type(8)));
typedef _Float16 half2v __attribute__((ext_vector_type(2)));
typedef float f32x16 __attribute__((ext_vector_type(16)));
typedef int int4v __attribute__((ext_vector_type(4)));

DEV f32x16 mfma16(half8 a, half8 b, f32x16 c) {
    return __builtin_amdgcn_mfma_f32_32x32x16_f16(a, b, c, 0, 0, 0);
}
DEV half8 h8(int4v v) { return __builtin_bit_cast(half8, v); }
DEV half8 ldh8(const _Float16* p) { return *(const half8*)p; }
DEV int pkrtz(float a, float b) {
    auto t = __builtin_amdgcn_cvt_pkrtz(a, b);
    return __builtin_bit_cast(int, t);
}
// pack two f32 -> f16x2 (RTZ), then packed relu
DEV int relupk(float a, float b) {
    int p = pkrtz(a, b);
    half2v h = __builtin_bit_cast(half2v, p);
    half2v z = {(_Float16)0.f, (_Float16)0.f};
    h = __builtin_elementwise_max(h, z);   // v_pk_max_f16
    return __builtin_bit_cast(int, h);
}
// v_permlane32_swap_b32: a[32..63] <-> b[0..31]
DEV void plswap(int& a, int& b) {
    asm("v_permlane32_swap_b32 %0, %1" : "+v"(a), "+v"(b));
}

DEV f32x16 zero16() {
    f32x16 z = {0.f,0.f,0.f,0.f,0.f,0.f,0.f,0.f,0.f,0.f,0.f,0.f,0.f,0.f,0.f,0.f};
    return z;
}

struct Frags { int4v c[4]; };  // activation B-fragments, K=64 (4 chunks of 16)

// relu + pack + cross-half swap: D-layout -> next layer's B-frag layout (verified R0)
DEV void repack(const f32x16& C0, const f32x16& C1, Frags& B) {
    int P0[8], P1[8];
#pragma unroll
    for (int q = 0; q < 8; ++q) {
        P0[q] = relupk(C0[2*q], C0[2*q+1]);
        P1[q] = relupk(C1[2*q], C1[2*q+1]);
    }
#pragma unroll
    for (int kk = 0; kk < 4; ++kk) {
        const int* Pm = (kk < 2) ? P0 : P1;
        int idx = 4 * (kk & 1);
        int a0 = Pm[idx + 0], b0 = Pm[idx + 2];
        int a1 = Pm[idx + 1], b1 = Pm[idx + 3];
        plswap(a0, b0);
        plswap(a1, b1);
        int4v nb; nb[0] = a0; nb[1] = a1; nb[2] = b0; nb[3] = b1;
        B.c[kk] = nb;
    }
}

// issue the 10 ds_read_b128 for one hidden layer's A-fragments (5 chunks x 2 m-halves)
DEV void loadA5(const _Float16* base, int lam, half8* A0, half8* A1) {
    const _Float16* p0 = base + lam * 8;
    const _Float16* p1 = base + 2560 + lam * 8;
#pragma unroll
    for (int kk = 0; kk < 5; ++kk) {
        A0[kk] = ldh8(p0 + kk * 512);
        A1[kk] = ldh8(p1 + kk * 512);
    }
}

// one tile (32 rows), hidden layer: 10 MFMA burst into C0 (feats 0-31), C1 (feats 32-63)
DEV void mfma_hid_t(const half8* A0, const half8* A1, int4v ones, const Frags& Bx,
                    f32x16& C0, f32x16& C1) {
    C0 = mfma16(A0[4], h8(ones), zero16());
    C1 = mfma16(A1[4], h8(ones), zero16());
#pragma unroll
    for (int kk = 0; kk < 4; ++kk) {
        half8 b = h8(Bx.c[kk]);
        C0 = mfma16(A0[kk], b, C0);
        C1 = mfma16(A1[kk], b, C1);
    }
}

// one tile, input layer (K=32, bias rides in x's k=28 slot): 4 MFMA burst
DEV void mfma_in_t(const half8* I, const Frags& Bx, f32x16& C0, f32x16& C1) {
    C0 = mfma16(I[0], h8(Bx.c[0]), zero16());
    C1 = mfma16(I[2], h8(Bx.c[0]), zero16());
    C0 = mfma16(I[1], h8(Bx.c[1]), C0);
    C1 = mfma16(I[3], h8(Bx.c[1]), C1);
}

// one tile, out layer: 5 MFMA burst (features 0..20 live in m=0 half)
DEV void mfma_out_t(const half8* Ao, int4v ones, const Frags& Bx, f32x16& C) {
    C = mfma16(Ao[4], h8(ones), zero16());
#pragma unroll
    for (int kk = 0; kk < 4; ++kk) C = mfma16(Ao[kk], h8(Bx.c[kk]), C);
}

DEV void store_out(const f32x16& C, int h, float* __restrict__ out, int row) {
    float* o = out + row * 21;
#pragma unroll
    for (int r = 0; r < 16; ++r) {
        int f = (r & 3) + 8 * (r >> 2) + 4 * h;
        if (f < 21) o[f] = __builtin_amdgcn_rcpf(1.f + __expf(-C[r]));
    }
}

DEV void load_x(const float* __restrict__ x, int row, int h, Frags& B) {
    // k = 16*kk + 8*h + e; x row stride 28 f32; k=28 slot carries 1.0 (bias rides in wI row 28)
    const float* xr = x + row * 28;
    float4 fa = *(const float4*)(xr + 8 * h);
    float4 fb = *(const float4*)(xr + 8 * h + 4);
    float4 fc = *(const float4*)(xr + 16 + 8 * h);
    float4 fd = (h == 0) ? *(const float4*)(xr + 20) : make_float4(1.f, 0.f, 0.f, 0.f);
    int4v c0, c1;
    c0[0] = pkrtz(fa.x, fa.y); c0[1] = pkrtz(fa.z, fa.w);
    c0[2] = pkrtz(fb.x, fb.y); c0[3] = pkrtz(fb.z, fb.w);
    c1[0] = pkrtz(fc.x, fc.y); c1[1] = pkrtz(fc.z, fc.w);
    c1[2] = pkrtz(fd.x, fd.y); c1[3] = pkrtz(fd.z, fd.w);
    B.c[0] = c0; B.c[1] = c1;
}

#define NT 512

__global__ __attribute__((amdgpu_flat_work_group_size(NT, NT), amdgpu_waves_per_eu(2, 2)))
void mlp_fused(
    const float* __restrict__ x, const float* __restrict__ W_in, const float* __restrict__ b_in,
    const float* __restrict__ W_hid, const float* __restrict__ b_hid,
    const float* __restrict__ W_out, const float* __restrict__ b_out,
    float* __restrict__ out) {
    // LDS weights in f16, A-fragment order: wH [l][m][kk 0..4][lam][e]; chunk kk=4 = bias column
    __shared__ __align__(16) _Float16 wH[51200];  // 10 x 2 x 5 x 64 x 8
    __shared__ __align__(16) _Float16 wI[2048];   // 2 x 2 x 64 x 8  (K=32, bias in k=28)
    __shared__ __align__(16) _Float16 wO[2560];   // 5 x 64 x 8      (features 0..20)

    const int tid = threadIdx.x;

    // zero phase: chunk-4 regions of wH, all of wI and wO
    for (int i = tid; i < 10240; i += NT) {   // wH bias chunks: [l][m][512]
        int l = i >> 10, rem = i & 1023, m = rem >> 9, off = rem & 511;
        wH[l * 5120 + m * 2560 + 2048 + off] = (_Float16)0.f;
    }
    for (int i = tid; i < 2048; i += NT) wI[i] = (_Float16)0.f;
    for (int i = tid; i < 2560; i += NT) wO[i] = (_Float16)0.f;
    __syncthreads();

    // fill phase (coalesced global reads, scattered LDS writes)
    for (int i = tid; i < 40960; i += NT) {   // W_hid [l][kin][o]
        int o = i & 63, kin = (i >> 6) & 63, l = i >> 12;
        int m = o >> 5, kk = kin >> 4, hh = (kin >> 3) & 1, e = kin & 7;
        int lam = hh * 32 + (o & 31);
        wH[l * 5120 + m * 2560 + kk * 512 + lam * 8 + e] = (_Float16)W_hid[i];
    }
    for (int i = tid; i < 640; i += NT) {     // b_hid -> wH chunk4, e=0, lam<32
        int l = i >> 6, f = i & 63, m = f >> 5, r = f & 31;
        wH[l * 5120 + m * 2560 + 2048 + r * 8] = (_Float16)b_hid[i];
    }
    for (int i = tid; i < 1792; i += NT) {    // W_in [28][64]
        int o = i & 63, kin = i >> 6;
        int m = o >> 5, kk = kin >> 4, hh = (kin >> 3) & 1, e = kin & 7;
        int lam = hh * 32 + (o & 31);
        wI[m * 1024 + kk * 512 + lam * 8 + e] = (_Float16)W_in[i];
    }
    for (int i = tid; i < 64; i += NT) {      // b_in -> wI k=28 slot: kk=1, hh=1, e=4
        int m = i >> 5;
        wI[m * 1024 + 512 + (32 + (i & 31)) * 8 + 4] = (_Float16)b_in[i];
    }
    for (int i = tid; i < 1344; i += NT) {    // W_out [64][21]
        int o = i % 21, kin = i / 21;
        int kk = kin >> 4, hh = (kin >> 3) & 1, e = kin & 7;
        int lam = hh * 32 + o;
        wO[kk * 512 + lam * 8 + e] = (_Float16)W_out[i];
    }
    for (int i = tid; i < 21; i += NT)        // b_out -> wO chunk4, e=0
        wO[4 * 512 + i * 8] = (_Float16)b_out[i];
    __syncthreads();

    const int w = tid >> 6, lam = tid & 63;
    const int col = lam & 31, h = lam >> 5;
    int4v ones; ones[0] = (h == 0) ? 0x3C00 : 0; ones[1] = 0; ones[2] = 0; ones[3] = 0;

    // hoist loop-invariant input/output layer fragments (reused by all iterations)
    half8 I[4], Ao[5];
    {
        const _Float16* p0 = wI + lam * 8;
        const _Float16* p1 = wI + 1024 + lam * 8;
        I[0] = ldh8(p0);       I[1] = ldh8(p0 + 512);
        I[2] = ldh8(p1);       I[3] = ldh8(p1 + 512);
        const _Float16* po = wO + lam * 8;
#pragma unroll
        for (int kk = 0; kk < 5; ++kk) Ao[kk] = ldh8(po + kk * 512);
    }

    // persistent: 256 blocks x 128 tiles; wave w owns tiles [w*16, w*16+16), 2 per iteration
    const int tbase = blockIdx.x * 128;
#pragma unroll 1
    for (int j = 0; j < 8; ++j) {
        int tA = tbase + w * 16 + 2 * j;
        int rowA = tA * 32 + col, rowB = rowA + 32;
        Frags BA, BB;
        load_x(x, rowA, h, BA);
        load_x(x, rowB, h, BB);

        half8 Fa0[5], Fa1[5], Fb0[5], Fb1[5];
        f32x16 CA0, CA1, CB0, CB1;

        // ---- two-stream skewed pipeline: B's burst hides A's repack, and vice versa ----
        mfma_in_t(I, BA, CA0, CA1);          // A burst (4 MFMA)
        loadA5(wH, lam, Fa0, Fa1);           // frags l=0, issued under A's burst
        mfma_in_t(I, BB, CB0, CB1);          // B burst
        repack(CA0, CA1, BA);                // A repack under B's burst

#pragma unroll
        for (int l2 = 0; l2 < 5; ++l2) {
            const _Float16* b0 = wH + (2 * l2) * 5120;
            // layer 2*l2 (frags Fa)
            mfma_hid_t(Fa0, Fa1, ones, BA, CA0, CA1);   // A burst (10 MFMA)
            loadA5(b0 + 5120, lam, Fb0, Fb1);           // prefetch layer 2*l2+1 under A's burst
            repack(CB0, CB1, BB);                       // B repack under A's burst
            mfma_hid_t(Fa0, Fa1, ones, BB, CB0, CB1);   // B burst
            repack(CA0, CA1, BA);                       // A repack under B's burst
            // layer 2*l2+1 (frags Fb)
            mfma_hid_t(Fb0, Fb1, ones, BA, CA0, CA1);   // A burst
            if (l2 < 4) loadA5(b0 + 10240, lam, Fa0, Fa1);  // prefetch layer 2*l2+2
            repack(CB0, CB1, BB);                       // B repack under A's burst
            mfma_hid_t(Fb0, Fb1, ones, BB, CB0, CB1);   // B burst
            repack(CA0, CA1, BA);                       // A repack under B's burst
        }

        // out layer
        f32x16 CoA, CoB;
        mfma_out_t(Ao, ones, BA, CoA);       // A burst (5 MFMA)
        repack(CB0, CB1, BB);                // B repack under A's burst
        mfma_out_t(Ao, ones, BB, CoB);       // B burst
        store_out(CoA, h, out, rowA);        // A sigmoid+store under B's burst
        store_out(CoB, h, out, rowB);
    }
}

extern "C" void kernel_launch(void* const* d_in, const int* in_sizes, int n_in,
                              void* d_out, int out_size, void* d_ws, size_t ws_size,
                              hipStream_t stream) {
    const float* x     = (const float*)d_in[0];
    const float* W_in  = (const float*)d_in[1];
    const float* b_in  = (const float*)d_in[2];
    const float* W_hid = (const float*)d_in[3];
    const float* b_hid = (const float*)d_in[4];
    const float* W_out = (const float*)d_in[5];
    const float* b_out = (const float*)d_in[6];
    float* out = (float*)d_out;
    mlp_fused<<<dim3(256), dim3(NT), 0, stream>>>(x, W_in, b_in, W_hid, b_hid, W_out, b_out, out);
}